// Round 6
// baseline (163.963 us; speedup 1.0000x reference)
//
#include <hip/hip_runtime.h>
#include <hip/hip_bf16.h>
#include <math.h>

// Problem constants
#define B_SZ 8
#define LSEQ 4096
#define NDIM 256
#define HDIM 256
#define MROWS (B_SZ * LSEQ)     // 32768
#define CH 64                   // chunk length (== GEMM m-tile)
#define NC (LSEQ / CH)          // 64 chunks per batch

#define BM 64
#define BN 128
#define BK 32
#define PAD 40                  // GEMM LDS row stride (halfs)
#define SSTR 68                 // scan LDS col stride (halfs)

typedef _Float16 half8 __attribute__((ext_vector_type(8)));
typedef _Float16 half4 __attribute__((ext_vector_type(4)));
typedef float fx4 __attribute__((ext_vector_type(4)));

// ---------------------------------------------------------------------------
// k_prep: weights -> fp16 (gamma folded into B, Cim negated), Lambda re/im,
// pow table P[i][n] = Lambda[n]^(i+1) (i < CH), and chunk-power table
// powC[k][n] = Lambda[n]^(CH*k) (k < NC) for the k_out carry lookback.
// grid 256 x 256.
// ---------------------------------------------------------------------------
__global__ void k_prep(const float* __restrict__ Bre, const float* __restrict__ Bim,
                       const float* __restrict__ Cre, const float* __restrict__ Cim,
                       const float* __restrict__ nu_log, const float* __restrict__ th_log,
                       _Float16* __restrict__ BreH, _Float16* __restrict__ BimH,
                       _Float16* __restrict__ CreH, _Float16* __restrict__ CimNH,
                       float* __restrict__ lamRe, float* __restrict__ lamIm,
                       float* __restrict__ powRe, float* __restrict__ powIm,
                       float* __restrict__ powCRe, float* __restrict__ powCIm) {
    int r = blockIdx.x;
    int t = threadIdx.x;
    // weights row r
    float nu  = expf(nu_log[r]);
    float th  = expf(th_log[r]);
    float mod = expf(-nu);
    float g   = sqrtf(fmaxf(1.0f - mod * mod, 0.0f));
    if (t == 0) {
        lamRe[r] = mod * cosf(th);
        lamIm[r] = mod * sinf(th);
    }
    int i = r * 256 + t;
    BreH[i]  = (_Float16)(Bre[i] * g);
    BimH[i]  = (_Float16)(Bim[i] * g);
    CreH[i]  = (_Float16)Cre[i];
    CimNH[i] = (_Float16)(-Cim[i]);
    // per-column params for the tables (column n = t)
    float nuN = expf(nu_log[t]);
    float thN = expf(th_log[t]);
    if (r < CH) {
        // pow row r: Lambda[t]^(r+1)
        float k  = (float)(r + 1);
        float mo = expf(-nuN * k);
        powRe[r * 256 + t] = mo * cosf(thN * k);
        powIm[r * 256 + t] = mo * sinf(thN * k);
        // powC row r: Lambda[t]^(CH*r)
        float kc = (float)(CH * r);
        float mc = expf(-nuN * kc);
        powCRe[r * 256 + t] = mc * cosf(thN * kc);
        powCIm[r * 256 + t] = mc * sinf(thN * kc);
    }
}

// ---------------------------------------------------------------------------
// k_buscan: fused  Bu = x @ B^T  GEMM  +  per-chunk local scan.
// Block 64m x 128n (m-tile == one chunk), 4 waves, BK=32 double-buffered LDS.
// After the K-loop the accumulators round-trip through LDS scan buffers
// (unioned with the GEMM staging LDS) laid out [col][row]; threads 0..127 run
// the fp32 per-column scan over 64 rows, write chunk finals, then all 256
// threads write the locally-scanned states (fp16) coalesced to global.
// MFMA 16x16x32 f16 mappings (verified m89/m91):
//   A/B frag lane L: row/col = L&15, k = (L>>4)*8 + j
//   D lane L: col = L&15, row = (L>>4)*4 + reg
// ---------------------------------------------------------------------------
__launch_bounds__(256)
__global__ void k_buscan(const float* __restrict__ x,
                         const _Float16* __restrict__ BreH,
                         const _Float16* __restrict__ BimH,
                         const float* __restrict__ lamRe,
                         const float* __restrict__ lamIm,
                         _Float16* __restrict__ stReH,
                         _Float16* __restrict__ stImH,
                         float* __restrict__ finRe,
                         float* __restrict__ finIm) {
    // 51200 B union: GEMM dbuf (25600 halfs) / scan buffers (17408 halfs)
    __shared__ __align__(16) _Float16 smem[25600];
    // GEMM layout (halfs): As p*12800+0, Br p*12800+2560, Bi p*12800+7680
    // scan layout: SRe at 0 (128*SSTR), SIm at 8704

    const int tid  = threadIdx.x;
    const int lane = tid & 63;
    const int wave = tid >> 6;
    const int wr   = wave >> 1;
    const int wc   = wave & 1;
    const int m0   = blockIdx.x * BM;
    const int n0   = blockIdx.y * BN;

    const int ar = tid >> 2, ac = (tid & 3) * 8;    // A staging map
    const int br = tid >> 1, bc = (tid & 1) * 16;   // B staging map

    const int fRC = lane & 15;
    const int fKg = (lane >> 4) * 8;

    fx4 accR[8], accI[8];
#pragma unroll
    for (int i = 0; i < 8; ++i) { accR[i] = (fx4)0.0f; accI[i] = (fx4)0.0f; }

    float4 xf0, xf1;
    half8 w0, w1, w2, w3;

    // prologue: stage k0=0 into buf 0
    {
        const float* xp = x + (size_t)(m0 + ar) * HDIM + ac;
        xf0 = *(const float4*)xp;
        xf1 = *(const float4*)(xp + 4);
        const _Float16* bp1 = BreH + (size_t)(n0 + br) * HDIM + bc;
        const _Float16* bp2 = BimH + (size_t)(n0 + br) * HDIM + bc;
        w0 = *(const half8*)bp1;  w1 = *(const half8*)(bp1 + 8);
        w2 = *(const half8*)bp2;  w3 = *(const half8*)(bp2 + 8);
        half8 hv;
        hv[0]=(_Float16)xf0.x; hv[1]=(_Float16)xf0.y; hv[2]=(_Float16)xf0.z; hv[3]=(_Float16)xf0.w;
        hv[4]=(_Float16)xf1.x; hv[5]=(_Float16)xf1.y; hv[6]=(_Float16)xf1.z; hv[7]=(_Float16)xf1.w;
        *(half8*)&smem[ar * PAD + ac] = hv;
        *(half8*)&smem[2560 + br * PAD + bc] = w0;  *(half8*)&smem[2560 + br * PAD + bc + 8] = w1;
        *(half8*)&smem[7680 + br * PAD + bc] = w2;  *(half8*)&smem[7680 + br * PAD + bc + 8] = w3;
    }
    __syncthreads();

    int p = 0;
    for (int k0 = 0; k0 < HDIM; k0 += BK) {
        const int po = p * 12800;
        const bool nx = (k0 + BK) < HDIM;
        if (nx) {
            const float* xp = x + (size_t)(m0 + ar) * HDIM + k0 + BK + ac;
            xf0 = *(const float4*)xp;
            xf1 = *(const float4*)(xp + 4);
            const _Float16* bp1 = BreH + (size_t)(n0 + br) * HDIM + k0 + BK + bc;
            const _Float16* bp2 = BimH + (size_t)(n0 + br) * HDIM + k0 + BK + bc;
            w0 = *(const half8*)bp1;  w1 = *(const half8*)(bp1 + 8);
            w2 = *(const half8*)bp2;  w3 = *(const half8*)(bp2 + 8);
        }
        half8 af[2], bRf[4], bIf[4];
#pragma unroll
        for (int sm = 0; sm < 2; ++sm)
            af[sm] = *(const half8*)&smem[po + (wr * 32 + sm * 16 + fRC) * PAD + fKg];
#pragma unroll
        for (int sn = 0; sn < 4; ++sn) {
            bRf[sn] = *(const half8*)&smem[po + 2560 + (wc * 64 + sn * 16 + fRC) * PAD + fKg];
            bIf[sn] = *(const half8*)&smem[po + 7680 + (wc * 64 + sn * 16 + fRC) * PAD + fKg];
        }
#pragma unroll
        for (int sm = 0; sm < 2; ++sm)
#pragma unroll
            for (int sn = 0; sn < 4; ++sn) {
                accR[sm * 4 + sn] = __builtin_amdgcn_mfma_f32_16x16x32_f16(af[sm], bRf[sn], accR[sm * 4 + sn], 0, 0, 0);
                accI[sm * 4 + sn] = __builtin_amdgcn_mfma_f32_16x16x32_f16(af[sm], bIf[sn], accI[sm * 4 + sn], 0, 0, 0);
            }
        if (nx) {
            const int qo = (p ^ 1) * 12800;
            half8 hv;
            hv[0]=(_Float16)xf0.x; hv[1]=(_Float16)xf0.y; hv[2]=(_Float16)xf0.z; hv[3]=(_Float16)xf0.w;
            hv[4]=(_Float16)xf1.x; hv[5]=(_Float16)xf1.y; hv[6]=(_Float16)xf1.z; hv[7]=(_Float16)xf1.w;
            *(half8*)&smem[qo + ar * PAD + ac] = hv;
            *(half8*)&smem[qo + 2560 + br * PAD + bc] = w0;  *(half8*)&smem[qo + 2560 + br * PAD + bc + 8] = w1;
            *(half8*)&smem[qo + 7680 + br * PAD + bc] = w2;  *(half8*)&smem[qo + 7680 + br * PAD + bc + 8] = w3;
        }
        __syncthreads();
        p ^= 1;
    }
    // loop-final __syncthreads guarantees all fragment reads drained -> smem reusable

    _Float16* SRe = smem;          // [col][row], stride SSTR
    _Float16* SIm = smem + 8704;

    // Phase A: accumulators -> scan LDS (transposed), fp16
    const int rBase = (lane >> 4) * 4;
#pragma unroll
    for (int sm = 0; sm < 2; ++sm)
#pragma unroll
        for (int sn = 0; sn < 4; ++sn) {
            int col = wc * 64 + sn * 16 + fRC;
            int row = wr * 32 + sm * 16 + rBase;
            half4 h1, h2;
#pragma unroll
            for (int reg = 0; reg < 4; ++reg) {
                h1[reg] = (_Float16)accR[sm * 4 + sn][reg];
                h2[reg] = (_Float16)accI[sm * 4 + sn][reg];
            }
            *(half4*)&SRe[col * SSTR + row] = h1;
            *(half4*)&SIm[col * SSTR + row] = h2;
        }
    __syncthreads();

    // Phase B: per-column scan over 64 rows (fp32 state), threads 0..127
    if (tid < BN) {
        int col = tid;
        int n = n0 + col;
        float lr = lamRe[n], li = lamIm[n];
        _Float16* cR = &SRe[col * SSTR];
        _Float16* cI = &SIm[col * SSTR];
        float sr = 0.0f, si = 0.0f;
#pragma unroll 8
        for (int r = 0; r < CH; ++r) {
            float ur = (float)cR[r];
            float ui = (float)cI[r];
            float nr = fmaf(lr, sr, fmaf(-li, si, ur));
            float ni = fmaf(lr, si, fmaf(li, sr, ui));
            sr = nr; si = ni;
            cR[r] = (_Float16)sr;
            cI[r] = (_Float16)si;
        }
        int bb = blockIdx.x >> 6, cc = blockIdx.x & 63;
        size_t f = ((size_t)(bb * NC + cc)) * NDIM + n;
        finRe[f] = sr;
        finIm[f] = si;
    }
    __syncthreads();

    // Phase C: coalesced write of locally-scanned states to global (fp16)
    {
        int row = tid >> 2;
        int cb  = (tid & 3) * 32;
        size_t gbase = (size_t)(m0 + row) * NDIM + n0 + cb;
#pragma unroll
        for (int g = 0; g < 4; ++g) {
            half8 h1, h2;
#pragma unroll
            for (int e = 0; e < 8; ++e) {
                int col = cb + g * 8 + e;
                h1[e] = SRe[col * SSTR + row];
                h2[e] = SIm[col * SSTR + row];
            }
            *(half8*)(stReH + gbase + g * 8) = h1;
            *(half8*)(stImH + gbase + g * 8) = h2;
        }
    }
}

// ---------------------------------------------------------------------------
// k_out: y = s @ CreH^T + sIm @ CimNH^T + x*D, with the chunk carry applied
// during A-staging: state[i] = local[i] + P[i]*carry  (P = Lambda^(i+1)).
// The carry itself is computed per-block via a parallel lookback:
//   car(c) = sum_{j<c} powC[c-1-j] * fin(j),   powC[k] = Lambda^(CH*k)
// (fins come from k_buscan; kernel boundary guarantees visibility).
// m-tile == one chunk (64 rows), so row index == local i.
// ---------------------------------------------------------------------------
__launch_bounds__(256)
__global__ void k_out(const _Float16* __restrict__ sReH,
                      const _Float16* __restrict__ sImH,
                      const _Float16* __restrict__ CreH,
                      const _Float16* __restrict__ CimNH,
                      const float* __restrict__ powRe,
                      const float* __restrict__ powIm,
                      const float* __restrict__ powCRe,
                      const float* __restrict__ powCIm,
                      const float* __restrict__ finRe,
                      const float* __restrict__ finIm,
                      const float* __restrict__ x,
                      const float* __restrict__ Dv,
                      float* __restrict__ y) {
    __shared__ __align__(16) _Float16 A1[2][BM * PAD];
    __shared__ __align__(16) _Float16 A2[2][BM * PAD];
    __shared__ __align__(16) _Float16 Cr[2][BN * PAD];
    __shared__ __align__(16) _Float16 Ci[2][BN * PAD];
    __shared__ __align__(16) float carL[2][NDIM];   // carry re/im per column

    const int tid  = threadIdx.x;
    const int lane = tid & 63;
    const int wave = tid >> 6;
    const int wr   = wave >> 1;
    const int wc   = wave & 1;
    const int m0   = blockIdx.x * BM;
    const int h0   = blockIdx.y * BN;
    const int bb   = blockIdx.x >> 6;   // batch
    const int cc   = blockIdx.x & 63;   // chunk within batch

    const int ar = tid >> 2, ac = (tid & 3) * 8;
    const int br = tid >> 1, bc = (tid & 1) * 16;

    const int fRC = lane & 15;
    const int fKg = (lane >> 4) * 8;

    // ---- carry lookback: thread t owns column n = t ----
    {
        const int n = tid;
        float cr = 0.0f, ci = 0.0f;
#pragma unroll 4
        for (int j = 0; j < cc; ++j) {
            int k = cc - 1 - j;
            float pr = powCRe[k * NDIM + n];
            float pi = powCIm[k * NDIM + n];
            size_t f = ((size_t)(bb * NC + j)) * NDIM + n;
            float fr = finRe[f];
            float fi = finIm[f];
            cr = fmaf(pr, fr, fmaf(-pi, fi, cr));
            ci = fmaf(pr, fi, fmaf( pi, fr, ci));
        }
        carL[0][n] = cr;
        carL[1][n] = ci;
    }
    __syncthreads();

    fx4 acc[8];
#pragma unroll
    for (int i = 0; i < 8; ++i) acc[i] = (fx4)0.0f;

    half8 s1, s2, c0a, c0b, c1a, c1b;
    float4 pr0, pr1, pi0, pi1, cr0, cr1, ci0, ci1;

#define LOAD_STAGE(K0)                                                          \
    {                                                                           \
        size_t aOff = (size_t)(m0 + ar) * NDIM + (K0) + ac;                     \
        s1 = *(const half8*)(sReH + aOff);                                      \
        s2 = *(const half8*)(sImH + aOff);                                      \
        size_t pOff = (size_t)ar * NDIM + (K0) + ac;                            \
        pr0 = *(const float4*)(powRe + pOff); pr1 = *(const float4*)(powRe + pOff + 4); \
        pi0 = *(const float4*)(powIm + pOff); pi1 = *(const float4*)(powIm + pOff + 4); \
        cr0 = *(const float4*)&carL[0][(K0) + ac]; cr1 = *(const float4*)&carL[0][(K0) + ac + 4]; \
        ci0 = *(const float4*)&carL[1][(K0) + ac]; ci1 = *(const float4*)&carL[1][(K0) + ac + 4]; \
        const _Float16* cp1 = CreH  + (size_t)(h0 + br) * NDIM + (K0) + bc;     \
        const _Float16* cp2 = CimNH + (size_t)(h0 + br) * NDIM + (K0) + bc;     \
        c0a = *(const half8*)cp1;  c0b = *(const half8*)(cp1 + 8);              \
        c1a = *(const half8*)cp2;  c1b = *(const half8*)(cp2 + 8);              \
    }

#define WRITE_STAGE(P)                                                          \
    {                                                                           \
        float prA[8] = {pr0.x,pr0.y,pr0.z,pr0.w,pr1.x,pr1.y,pr1.z,pr1.w};       \
        float piA[8] = {pi0.x,pi0.y,pi0.z,pi0.w,pi1.x,pi1.y,pi1.z,pi1.w};       \
        float crA[8] = {cr0.x,cr0.y,cr0.z,cr0.w,cr1.x,cr1.y,cr1.z,cr1.w};       \
        float ciA[8] = {ci0.x,ci0.y,ci0.z,ci0.w,ci1.x,ci1.y,ci1.z,ci1.w};       \
        half8 h1, h2;                                                           \
        _Pragma("unroll")                                                       \
        for (int e = 0; e < 8; ++e) {                                           \
            float ur = fmaf(prA[e], crA[e], fmaf(-piA[e], ciA[e], (float)s1[e])); \
            float ui = fmaf(prA[e], ciA[e], fmaf( piA[e], crA[e], (float)s2[e])); \
            h1[e] = (_Float16)ur; h2[e] = (_Float16)ui;                         \
        }                                                                       \
        *(half8*)&A1[P][ar * PAD + ac] = h1;                                    \
        *(half8*)&A2[P][ar * PAD + ac] = h2;                                    \
        *(half8*)&Cr[P][br * PAD + bc] = c0a;  *(half8*)&Cr[P][br * PAD + bc + 8] = c0b; \
        *(half8*)&Ci[P][br * PAD + bc] = c1a;  *(half8*)&Ci[P][br * PAD + bc + 8] = c1b; \
    }

    LOAD_STAGE(0);
    WRITE_STAGE(0);
    __syncthreads();

    int p = 0;
    for (int k0 = 0; k0 < NDIM; k0 += BK) {
        const bool nx = (k0 + BK) < NDIM;
        if (nx) LOAD_STAGE(k0 + BK);
        half8 a1[2], a2[2], bRf[4], bIf[4];
#pragma unroll
        for (int sm = 0; sm < 2; ++sm) {
            a1[sm] = *(const half8*)&A1[p][(wr * 32 + sm * 16 + fRC) * PAD + fKg];
            a2[sm] = *(const half8*)&A2[p][(wr * 32 + sm * 16 + fRC) * PAD + fKg];
        }
#pragma unroll
        for (int sn = 0; sn < 4; ++sn) {
            bRf[sn] = *(const half8*)&Cr[p][(wc * 64 + sn * 16 + fRC) * PAD + fKg];
            bIf[sn] = *(const half8*)&Ci[p][(wc * 64 + sn * 16 + fRC) * PAD + fKg];
        }
#pragma unroll
        for (int sm = 0; sm < 2; ++sm)
#pragma unroll
            for (int sn = 0; sn < 4; ++sn) {
                acc[sm * 4 + sn] = __builtin_amdgcn_mfma_f32_16x16x32_f16(a1[sm], bRf[sn], acc[sm * 4 + sn], 0, 0, 0);
                acc[sm * 4 + sn] = __builtin_amdgcn_mfma_f32_16x16x32_f16(a2[sm], bIf[sn], acc[sm * 4 + sn], 0, 0, 0);
            }
        if (nx) WRITE_STAGE(p ^ 1);
        __syncthreads();
        p ^= 1;
    }

    float d[4];
#pragma unroll
    for (int sn = 0; sn < 4; ++sn) d[sn] = Dv[h0 + wc * 64 + sn * 16 + fRC];

    const int rBase = (lane >> 4) * 4;
#pragma unroll
    for (int sm = 0; sm < 2; ++sm)
#pragma unroll
        for (int sn = 0; sn < 4; ++sn) {
            int h = h0 + wc * 64 + sn * 16 + fRC;
#pragma unroll
            for (int reg = 0; reg < 4; ++reg) {
                int m = m0 + wr * 32 + sm * 16 + rBase + reg;
                size_t idx = (size_t)m * HDIM + h;
                y[idx] = fmaf(x[idx], d[sn], acc[sm * 4 + sn][reg]);
            }
        }
#undef LOAD_STAGE
#undef WRITE_STAGE
}

// ---------------------------------------------------------------------------
extern "C" void kernel_launch(void* const* d_in, const int* in_sizes, int n_in,
                              void* d_out, int out_size, void* d_ws, size_t ws_size,
                              hipStream_t stream) {
    const float* x      = (const float*)d_in[0];
    const float* B_re   = (const float*)d_in[1];
    const float* B_im   = (const float*)d_in[2];
    const float* C_re   = (const float*)d_in[3];
    const float* C_im   = (const float*)d_in[4];
    const float* nu_log = (const float*)d_in[5];
    const float* th_log = (const float*)d_in[6];
    const float* D      = (const float*)d_in[7];
    float* y = (float*)d_out;

    char* p = (char*)d_ws;
    _Float16* stReH = (_Float16*)p;  p += (size_t)MROWS * NDIM * 2;
    _Float16* stImH = (_Float16*)p;  p += (size_t)MROWS * NDIM * 2;
    _Float16* BreH  = (_Float16*)p;  p += (size_t)NDIM * HDIM * 2;
    _Float16* BimH  = (_Float16*)p;  p += (size_t)NDIM * HDIM * 2;
    _Float16* CreH  = (_Float16*)p;  p += (size_t)HDIM * NDIM * 2;
    _Float16* CimNH = (_Float16*)p;  p += (size_t)HDIM * NDIM * 2;
    float* lamRe  = (float*)p;  p += NDIM * 4;
    float* lamIm  = (float*)p;  p += NDIM * 4;
    float* powRe  = (float*)p;  p += (size_t)CH * NDIM * 4;
    float* powIm  = (float*)p;  p += (size_t)CH * NDIM * 4;
    float* powCRe = (float*)p;  p += (size_t)NC * NDIM * 4;
    float* powCIm = (float*)p;  p += (size_t)NC * NDIM * 4;
    float* finRe  = (float*)p;  p += (size_t)B_SZ * NC * NDIM * 4;
    float* finIm  = (float*)p;  p += (size_t)B_SZ * NC * NDIM * 4;

    k_prep<<<NDIM, 256, 0, stream>>>(B_re, B_im, C_re, C_im, nu_log, th_log,
                                     BreH, BimH, CreH, CimNH, lamRe, lamIm,
                                     powRe, powIm, powCRe, powCIm);

    dim3 gGemm(MROWS / BM, NDIM / BN);
    k_buscan<<<gGemm, 256, 0, stream>>>(x, BreH, BimH, lamRe, lamIm,
                                        stReH, stImH, finRe, finIm);

    dim3 gOut(MROWS / BM, HDIM / BN);
    k_out<<<gOut, 256, 0, stream>>>(stReH, stImH, CreH, CimNH,
                                    powRe, powIm, powCRe, powCIm,
                                    finRe, finIm, x, D, y);
}